// Round 11
// baseline (5716.243 us; speedup 1.0000x reference)
//
#include <hip/hip_runtime.h>
#include <cstdint>
#include <cstddef>

#define DD 12
#define NNODE 32768
#define LTOK 3
#define KCH 4
#define HD 128
#define NC_STEP 896
#define KD_STEP 640
#define NC_EMB 128
#define KD_EMB 384
#define LSTR 72   // padded LDS row stride (u16) for staging/fragments
#define ESTR 68   // padded epilogue row stride (u16): quad bank-spans disjoint

typedef unsigned short u16;
typedef __attribute__((ext_vector_type(8))) __bf16 bf16x8;
typedef __attribute__((ext_vector_type(4))) float f32x4;

__device__ __forceinline__ float bf2f(unsigned int u) {
  union { unsigned int i; float f; } v; v.i = (u & 0xffffu) << 16; return v.f;
}
__device__ __forceinline__ u16 f2bf(float f) {
  union { float f; unsigned int i; } v; v.f = f;
  unsigned int x = v.i;
  return (u16)((x + 0x7fffu + ((x >> 16) & 1u)) >> 16);
}
__device__ __forceinline__ float sigm(float x) { return 1.f / (1.f + __expf(-x)); }
__device__ __forceinline__ float tanh_fast(float x) { return 1.f - 2.f / (1.f + __expf(2.f * x)); }
__device__ __forceinline__ uint4 pack8(const float* p) {
  float4 a = *(const float4*)p;
  float4 b = *(const float4*)(p + 4);
  uint4 r;
  r.x = (unsigned)f2bf(a.x) | ((unsigned)f2bf(a.y) << 16);
  r.y = (unsigned)f2bf(a.z) | ((unsigned)f2bf(a.w) << 16);
  r.z = (unsigned)f2bf(b.x) | ((unsigned)f2bf(b.y) << 16);
  r.w = (unsigned)f2bf(b.z) | ((unsigned)f2bf(b.w) << 16);
  return r;
}

// ---------------------------------------------------------------------------
// Tiled bf16 MFMA GEMM: out[M,NC] = A[M,KD] @ B[NC,KD]^T + bias.
// MODE 0 (step): A[r,0:512]=h_prev[children(r)] bf16, A[r,512:640]=t[r,:] f32
//                -> out = pre (bf16) via padded-LDS coalescing transpose
// MODE 1 (embed): A[r,0:384]=Ebf[tokens[r,0..2]] -> out = t (f32)
// grid = (row_tiles, col_tiles): row-fastest => col-tiles of one row-slab land
// on the SAME XCD (linear idx differs by gridDim.x) -> A fetched once per XCD.
// Register-pipelined staging: idx hoisted to prologue, load(k+1) issued
// before MFMA(k).
// ---------------------------------------------------------------------------
template <int MODE, int NC, int KD>
__global__ __launch_bounds__(256) void gemm_k(
    const u16* __restrict__ Abf, const float* __restrict__ Tf,
    const int* __restrict__ gidx, const u16* __restrict__ B,
    const float* __restrict__ bias, u16* __restrict__ outb,
    float* __restrict__ outf, const u16* __restrict__ zbuf)
{
  __shared__ u16 lds[2 * 128 * LSTR];   // 36 KB: As | Bs, reused by epilogue
  u16* As = lds;
  u16* Bs = lds + 128 * LSTR;
  const int t = threadIdx.x;
  const int w = t >> 6;
  const int L = t & 63;
  const int q = L >> 4;
  const int lrow8 = L >> 3;
  const int sub = L & 7;
  const int row0 = blockIdx.x * 128;
  const int col0 = blockIdx.y * 128;

  f32x4 acc[4][4];
#pragma unroll
  for (int a = 0; a < 4; ++a)
#pragma unroll
    for (int b = 0; b < 4; ++b)
      acc[a][b] = f32x4{0.f, 0.f, 0.f, 0.f};

  const int mrow = (w & 1) * 64;
  const int ncol = (w >> 1) * 64;

  // ---- prologue: hoist gather indices (kills in-loop idx->A chain) ----
  int4 cidx[4];
#pragma unroll
  for (int jj = 0; jj < 4; ++jj) {
    const int rit = w * 32 + jj * 8 + lrow8;
    if constexpr (MODE == 0) {
      cidx[jj] = *(const int4*)&gidx[(row0 + rit) * KCH];
    } else {
      cidx[jj].x = gidx[(row0 + rit) * LTOK + 0];
      cidx[jj].y = gidx[(row0 + rit) * LTOK + 1];
      cidx[jj].z = gidx[(row0 + rit) * LTOK + 2];
    }
  }

  auto stage_load = [&](int k0, uint4* va, uint4* vb) {
#pragma unroll
    for (int jj = 0; jj < 4; ++jj) {
      const int rit = w * 32 + jj * 8 + lrow8;
      if constexpr (MODE == 0) {
        if (k0 < 4 * HD) {
          const int id = ((const int*)&cidx[jj])[k0 >> 7];
          const u16* base = (id >= 1) ? (Abf + (size_t)(id - 1) * HD) : zbuf;
          va[jj] = *(const uint4*)(base + (k0 & 127) + sub * 8);
        } else {
          va[jj] = pack8(Tf + (size_t)(row0 + rit) * HD + (k0 - 4 * HD) + sub * 8);
        }
      } else {
        const int tok = ((const int*)&cidx[jj])[k0 >> 7];
        va[jj] = *(const uint4*)(Abf + (size_t)tok * HD + (k0 & 127) + sub * 8);
      }
      vb[jj] = *(const uint4*)(B + (size_t)(col0 + rit) * KD + k0 + sub * 8);
    }
  };

  uint4 va[4], vb[4], na[4], nb[4];
  stage_load(0, va, vb);

#pragma unroll
  for (int k0 = 0; k0 < KD; k0 += 64) {
    __syncthreads();
#pragma unroll
    for (int jj = 0; jj < 4; ++jj) {
      const int r = w * 32 + jj * 8 + lrow8;
      *(uint4*)&As[r * LSTR + sub * 8] = va[jj];
      *(uint4*)&Bs[r * LSTR + sub * 8] = vb[jj];
    }
    __syncthreads();
    if (k0 + 64 < KD) stage_load(k0 + 64, na, nb);   // in flight during MFMA
#pragma unroll
    for (int ks = 0; ks < 2; ++ks) {
      bf16x8 af[4], bfr[4];
#pragma unroll
      for (int mt = 0; mt < 4; ++mt)
        af[mt] = *(const bf16x8*)&As[(mrow + mt * 16 + (L & 15)) * LSTR + ks * 32 + q * 8];
#pragma unroll
      for (int nt = 0; nt < 4; ++nt)
        bfr[nt] = *(const bf16x8*)&Bs[(ncol + nt * 16 + (L & 15)) * LSTR + ks * 32 + q * 8];
#pragma unroll
      for (int mt = 0; mt < 4; ++mt)
#pragma unroll
        for (int nt = 0; nt < 4; ++nt)
          acc[mt][nt] = __builtin_amdgcn_mfma_f32_16x16x32_bf16(af[mt], bfr[nt], acc[mt][nt], 0, 0, 0);
    }
#pragma unroll
    for (int jj = 0; jj < 4; ++jj) { va[jj] = na[jj]; vb[jj] = nb[jj]; }
  }

  // epilogue: C/D layout col=lane&15, row=(lane>>4)*4+i (probe-verified R8)
  if constexpr (MODE == 0) {
    __syncthreads();                  // all waves done reading As/Bs
    u16* epi = lds + w * (64 * ESTR); // private 64x68 region per wave
#pragma unroll
    for (int nt = 0; nt < 4; ++nt) {
      const int c = nt * 16 + (L & 15);
      const float bb = bias[col0 + ncol + c];
#pragma unroll
      for (int mt = 0; mt < 4; ++mt)
#pragma unroll
        for (int i = 0; i < 4; ++i)
          epi[(mt * 16 + q * 4 + i) * ESTR + c] = f2bf(acc[mt][nt][i] + bb);
    }
    // wave-local readback (lgkmcnt ordering, no barrier needed)
#pragma unroll
    for (int it = 0; it < 8; ++it) {
      const int rr = it * 8 + (L >> 3);
      const uint4 v = *(const uint4*)&epi[rr * ESTR + (L & 7) * 8];
      const int grow = row0 + mrow + rr;
      const int gcol = col0 + ncol + (L & 7) * 8;
      *(uint4*)&outb[(size_t)grow * NC + gcol] = v;
    }
  } else {
#pragma unroll
    for (int nt = 0; nt < 4; ++nt) {
      const int col = col0 + ncol + nt * 16 + (L & 15);
      const float bb = bias[col];
#pragma unroll
      for (int mt = 0; mt < 4; ++mt)
#pragma unroll
        for (int i = 0; i < 4; ++i) {
          const int row = row0 + mrow + mt * 16 + q * 4 + i;
          outf[(size_t)row * NC + col] = acc[mt][nt][i] + bb;
        }
    }
  }
}

// ---------------------------------------------------------------------------
// LSTM cell: f = sum_k sig(pre_fk)*c_k ; gates ; c (f32), h (bf16), t += h (f32)
// ---------------------------------------------------------------------------
__global__ __launch_bounds__(256) void cell_k(
    const u16* __restrict__ pre, const int* __restrict__ idxs,
    const float* __restrict__ c_prev, float* __restrict__ c_cur,
    u16* __restrict__ h_cur, float* __restrict__ t_io)
{
  const int g = blockIdx.x * 256 + threadIdx.x;
  const int r = g >> 7;
  const int j = g & 127;
  const u16* pr = pre + (size_t)r * NC_STEP;
  float f = 0.f;
#pragma unroll
  for (int k = 0; k < KCH; ++k) {
    const int id = idxs[r * KCH + k];
    const float cg = (id >= 1) ? c_prev[(size_t)(id - 1) * HD + j] : 0.f;
    f += sigm(bf2f(pr[k * HD + j])) * cg;
  }
  const float iv = sigm(bf2f(pr[4 * HD + j]));
  const float uv = tanh_fast(bf2f(pr[5 * HD + j]));
  const float ov = sigm(bf2f(pr[6 * HD + j]));
  const float cn = iv * uv + f;
  const float hv = ov * tanh_fast(cn);
  c_cur[g] = cn;
  h_cur[g] = f2bf(hv);
  t_io[g] = t_io[g] + hv;
}

__global__ __launch_bounds__(256) void conv_k(const float* __restrict__ src,
                                              u16* __restrict__ dst, int n4)
{
  const int g = blockIdx.x * 256 + threadIdx.x;
  if (g < n4) {
    float4 v = ((const float4*)src)[g];
    ((ushort4*)dst)[g] = make_ushort4(f2bf(v.x), f2bf(v.y), f2bf(v.z), f2bf(v.w));
  }
}

// Build U_big[l][896][640] (bf16) = [Uf;Uiuo | W_w(mapped)] + fused f32 biases.
__global__ __launch_bounds__(256) void prep_k(
    const float* __restrict__ Uf_w, const float* __restrict__ Uf_b,
    const float* __restrict__ Uiuo_w, const float* __restrict__ Uiuo_b,
    const float* __restrict__ W_w, const float* __restrict__ W_b,
    u16* __restrict__ Ubig, float* __restrict__ biasbig)
{
  const int l = blockIdx.y;
  const int e = blockIdx.x * 256 + threadIdx.x;
  const int c = e / KD_STEP;
  const int k = e % KD_STEP;
  float v;
  if (k < 512) {
    v = (c < 512) ? Uf_w[((size_t)l * 512 + c) * 512 + k]
                  : Uiuo_w[((size_t)l * 384 + (c - 512)) * 512 + k];
  } else {
    const int q = k - 512;
    const int wr = (c < 512) ? (c & 127) : (128 + (c - 512));
    v = W_w[((size_t)l * 512 + wr) * 128 + q];
  }
  Ubig[((size_t)l * 896 + c) * 640 + k] = f2bf(v);
  if (e < 896) {
    const float b = (e < 512)
        ? (Uf_b[l * 512 + e] + W_b[l * 512 + (e & 127)])
        : (Uiuo_b[l * 384 + (e - 512)] + W_b[l * 512 + 128 + (e - 512)]);
    biasbig[l * 896 + e] = b;
  }
}

// Output (FLOAT32): hx = tile(t_final,2), cx = tile(c_final,2).
__global__ __launch_bounds__(256) void fin_k(
    const float* __restrict__ t_fin, const float* __restrict__ c_fin,
    float* __restrict__ out)
{
  const size_t NH = (size_t)NNODE * HD;
  const size_t g = (size_t)blockIdx.x * 256 + threadIdx.x;
  const float h = t_fin[g];
  const float c = c_fin[g];
  out[g] = h;
  out[NH + g] = h;
  out[2 * NH + g] = c;
  out[3 * NH + g] = c;
}

extern "C" void kernel_launch(void* const* d_in, const int* in_sizes, int n_in,
                              void* d_out, int out_size, void* d_ws, size_t ws_size,
                              hipStream_t stream)
{
  (void)in_sizes; (void)n_in; (void)out_size; (void)ws_size;
  const int*   tokens  = (const int*)d_in[0];
  const int*   indices = (const int*)d_in[1];
  const float* E       = (const float*)d_in[2];
  const float* lin_w   = (const float*)d_in[3];
  const float* lin_b   = (const float*)d_in[4];
  const float* Uf_w    = (const float*)d_in[5];
  const float* Uf_b    = (const float*)d_in[6];
  const float* Uiuo_w  = (const float*)d_in[7];
  const float* Uiuo_b  = (const float*)d_in[8];
  const float* W_w     = (const float*)d_in[9];
  const float* W_b     = (const float*)d_in[10];
  float* out = (float*)d_out;   // FLOAT32 output (R8-proven)

  const size_t NH = (size_t)NNODE * HD;

  char* ws = (char*)d_ws;
  size_t off = 0;
  auto alloc = [&](size_t bytes) -> void* {
    void* p = ws + off;
    off = (off + bytes + 255) & ~(size_t)255;
    return p;
  };
  u16*   Ubig    = (u16*)alloc((size_t)2 * 896 * 640 * 2);
  float* biasbig = (float*)alloc(2 * 896 * 4);
  u16*   Ebf     = (u16*)alloc((size_t)50000 * HD * 2);
  u16*   Lbf     = (u16*)alloc((size_t)HD * KD_EMB * 2);
  float* tslice  = (float*)alloc(NH * 4);
  u16*   h0a     = (u16*)alloc(NH * 2);
  u16*   h0b     = (u16*)alloc(NH * 2);
  u16*   h1a     = (u16*)alloc(NH * 2);
  u16*   h1b     = (u16*)alloc(NH * 2);
  float* c0a     = (float*)alloc(NH * 4);
  float* c0b     = (float*)alloc(NH * 4);
  float* c1a     = (float*)alloc(NH * 4);
  float* c1b     = (float*)alloc(NH * 4);
  u16*   pre     = (u16*)alloc((size_t)NNODE * NC_STEP * 2);
  u16*   zbuf    = (u16*)alloc(512);

  u16*   h0[2] = {h0a, h0b};
  u16*   h1[2] = {h1a, h1b};
  float* c0[2] = {c0a, c0b};
  float* c1[2] = {c1a, c1b};

  hipMemsetAsync(zbuf, 0, 512, stream);
  hipMemsetAsync(h0[0], 0, NH * 2, stream);
  hipMemsetAsync(h1[0], 0, NH * 2, stream);
  hipMemsetAsync(c0[0], 0, NH * 4, stream);
  hipMemsetAsync(c1[0], 0, NH * 4, stream);
  prep_k<<<dim3(2240, 2), 256, 0, stream>>>(Uf_w, Uf_b, Uiuo_w, Uiuo_b, W_w, W_b,
                                            Ubig, biasbig);
  conv_k<<<dim3((50000 * HD / 4 + 255) / 256), 256, 0, stream>>>(E, Ebf, 50000 * HD / 4);
  conv_k<<<dim3((HD * KD_EMB / 4 + 255) / 256), 256, 0, stream>>>(lin_w, Lbf, HD * KD_EMB / 4);

  for (int d = 0; d < DD; ++d) {
    const int ri = d & 1, wi = (d + 1) & 1;
    const int* idxd = indices + (size_t)d * NNODE * KCH;
    const int* tokd = tokens + (size_t)d * NNODE * LTOK;

    // tslice (f32) = gather(Ebf, tokens[d]) @ Lbf^T + lin_b
    gemm_k<1, NC_EMB, KD_EMB><<<dim3(NNODE / 128, 1), 256, 0, stream>>>(
        Ebf, nullptr, tokd, Lbf, lin_b, nullptr, tslice, zbuf);

    for (int l = 0; l < 2; ++l) {
      const u16*   hp = (l == 0) ? h0[ri] : h1[ri];
      u16*         hc = (l == 0) ? h0[wi] : h1[wi];
      const float* cp = (l == 0) ? c0[ri] : c1[ri];
      float*       cc = (l == 0) ? c0[wi] : c1[wi];
      const u16* Ul = Ubig + (size_t)l * 896 * 640;
      const float* bl = biasbig + l * 896;
      gemm_k<0, NC_STEP, KD_STEP><<<dim3(NNODE / 128, NC_STEP / 128), 256, 0, stream>>>(
          hp, tslice, idxd, Ul, bl, pre, nullptr, zbuf);
      cell_k<<<dim3((int)(NH / 256)), 256, 0, stream>>>(
          pre, idxd, cp, cc, hc, tslice);
    }
  }
  // after d=11: tslice = t_final, c1[0] = c_final
  fin_k<<<dim3((int)(NH / 256)), 256, 0, stream>>>(tslice, c1[0], out);
}

// Round 12
// 2362.363 us; speedup vs baseline: 2.4197x; 2.4197x over previous
//
#include <hip/hip_runtime.h>
#include <cstdint>
#include <cstddef>

#define DD 12
#define NNODE 32768
#define LTOK 3
#define KCH 4
#define HD 128
#define NC_STEP 896
#define KD_STEP 640
#define NC_EMB 128
#define KD_EMB 384

typedef unsigned short u16;
typedef __attribute__((ext_vector_type(8))) __bf16 bf16x8;
typedef __attribute__((ext_vector_type(4))) float f32x4;

__device__ __forceinline__ float bf2f(unsigned int u) {
  union { unsigned int i; float f; } v; v.i = (u & 0xffffu) << 16; return v.f;
}
__device__ __forceinline__ u16 f2bf(float f) {
  union { float f; unsigned int i; } v; v.f = f;
  unsigned int x = v.i;
  return (u16)((x + 0x7fffu + ((x >> 16) & 1u)) >> 16);
}
__device__ __forceinline__ float sigm(float x) { return 1.f / (1.f + __expf(-x)); }
__device__ __forceinline__ float tanh_fast(float x) { return 1.f - 2.f / (1.f + __expf(2.f * x)); }
__device__ __forceinline__ uint4 pack8(const float* p) {
  float4 a = *(const float4*)p;
  float4 b = *(const float4*)(p + 4);
  uint4 r;
  r.x = (unsigned)f2bf(a.x) | ((unsigned)f2bf(a.y) << 16);
  r.y = (unsigned)f2bf(a.z) | ((unsigned)f2bf(a.w) << 16);
  r.z = (unsigned)f2bf(b.x) | ((unsigned)f2bf(b.y) << 16);
  r.w = (unsigned)f2bf(b.z) | ((unsigned)f2bf(b.w) << 16);
  return r;
}
__device__ __forceinline__ void async16(const void* g, void* l) {
  __builtin_amdgcn_global_load_lds((const __attribute__((address_space(1))) unsigned int*)g,
                                   (__attribute__((address_space(3))) unsigned int*)l, 16, 0, 0);
}

// ---------------------------------------------------------------------------
// Tiled bf16 MFMA GEMM: out[M,NC] = A[M,KD] @ B[NC,KD]^T + bias.
// MODE 0 (step): A[r,0:512]=h_prev[children(r)] bf16 (async LDS),
//                A[r,512:640]=t[r,:] f32 (VGPR path) -> out = pre (bf16)
// MODE 1 (embed): A[r,0:384]=Ebf[tokens[r,0..2]] (async) -> out = t (f32)
// 128x128 tile, BK=64, 4 waves, 4x4 16x16x32 MFMA.
// LDS rows are UNPADDED 128 B (required by global_load_lds: lane lands at
// base+L*16). Bank conflicts avoided by XOR swizzle: lane (r,s) fetches
// global k-chunk s^r, so fragment reads hit chunk (ks*4+q)^(L&7) -> 2-way max.
// grid = (row_tiles, col_tiles) row-fastest (R9's XCD-local A reuse).
// Epilogue = R9 scatter (measured best).
// ---------------------------------------------------------------------------
template <int MODE, int NC, int KD>
__global__ __launch_bounds__(256) void gemm_k(
    const u16* __restrict__ Abf, const float* __restrict__ Tf,
    const int* __restrict__ gidx, const u16* __restrict__ B,
    const float* __restrict__ bias, u16* __restrict__ outb,
    float* __restrict__ outf, const u16* __restrict__ zbuf)
{
  __shared__ u16 As[128 * 64];
  __shared__ u16 Bs[128 * 64];
  const int t = threadIdx.x;
  const int w = t >> 6;
  const int L = t & 63;
  const int q = L >> 4;
  const int lrow8 = L >> 3;       // row within 8-row slab
  const int sub = L & 7;          // 16B landing slot within 128B row
  const int swz = sub ^ lrow8;    // global chunk this lane fetches
  const int row0 = blockIdx.x * 128;
  const int col0 = blockIdx.y * 128;

  f32x4 acc[4][4];
#pragma unroll
  for (int a = 0; a < 4; ++a)
#pragma unroll
    for (int b = 0; b < 4; ++b)
      acc[a][b] = f32x4{0.f, 0.f, 0.f, 0.f};

  const int mrow = (w & 1) * 64;
  const int ncol = (w >> 1) * 64;

  // hoist gather indices
  int4 cidx[4];
#pragma unroll
  for (int jj = 0; jj < 4; ++jj) {
    const int rit = w * 32 + jj * 8 + lrow8;
    if constexpr (MODE == 0) {
      cidx[jj] = *(const int4*)&gidx[(row0 + rit) * KCH];
    } else {
      cidx[jj].x = gidx[(row0 + rit) * LTOK + 0];
      cidx[jj].y = gidx[(row0 + rit) * LTOK + 1];
      cidx[jj].z = gidx[(row0 + rit) * LTOK + 2];
    }
  }

#pragma unroll
  for (int k0 = 0; k0 < KD; k0 += 64) {
    __syncthreads();   // prior MFMA reads complete before LDS overwrite
    if (MODE == 1 || k0 < 4 * HD) {
      // async direct-to-LDS staging, swizzled global chunk
#pragma unroll
      for (int jj = 0; jj < 4; ++jj) {
        const int id = ((const int*)&cidx[jj])[k0 >> 7];
        const u16* base;
        if constexpr (MODE == 0)
          base = (id >= 1) ? (Abf + (size_t)(id - 1) * HD) : zbuf;
        else
          base = Abf + (size_t)id * HD;
        async16(base + (k0 & 127) + swz * 8, &As[(w * 32 + jj * 8) * 64]);
        const int rit = w * 32 + jj * 8 + lrow8;
        async16(B + (size_t)(col0 + rit) * KD + k0 + swz * 8, &Bs[(w * 32 + jj * 8) * 64]);
      }
    } else {
      // t-columns: f32 -> bf16 VGPR path for A, async for B
      uint4 va[4];
#pragma unroll
      for (int jj = 0; jj < 4; ++jj) {
        const int rit = w * 32 + jj * 8 + lrow8;
        va[jj] = pack8(Tf + (size_t)(row0 + rit) * HD + (k0 - 4 * HD) + swz * 8);
        async16(B + (size_t)(col0 + rit) * KD + k0 + swz * 8, &Bs[(w * 32 + jj * 8) * 64]);
      }
#pragma unroll
      for (int jj = 0; jj < 4; ++jj)
        *(uint4*)&As[(w * 32 + jj * 8 + lrow8) * 64 + sub * 8] = va[jj];
    }
    __syncthreads();   // drains vmcnt (async LDS) + lgkm
#pragma unroll
    for (int ks = 0; ks < 2; ++ks) {
      bf16x8 af[4], bfr[4];
      const int pc = ((ks * 4 + q) ^ (L & 7)) * 8;   // swizzled physical chunk
#pragma unroll
      for (int mt = 0; mt < 4; ++mt)
        af[mt] = *(const bf16x8*)&As[(mrow + mt * 16 + (L & 15)) * 64 + pc];
#pragma unroll
      for (int nt = 0; nt < 4; ++nt)
        bfr[nt] = *(const bf16x8*)&Bs[(ncol + nt * 16 + (L & 15)) * 64 + pc];
#pragma unroll
      for (int mt = 0; mt < 4; ++mt)
#pragma unroll
        for (int nt = 0; nt < 4; ++nt)
          acc[mt][nt] = __builtin_amdgcn_mfma_f32_16x16x32_bf16(af[mt], bfr[nt], acc[mt][nt], 0, 0, 0);
    }
  }

  // epilogue (R9 scatter): C/D layout col=lane&15, row=(lane>>4)*4+i
#pragma unroll
  for (int nt = 0; nt < 4; ++nt) {
    const int col = col0 + ncol + nt * 16 + (L & 15);
    const float bb = bias[col];
#pragma unroll
    for (int mt = 0; mt < 4; ++mt) {
#pragma unroll
      for (int i = 0; i < 4; ++i) {
        const int row = row0 + mrow + mt * 16 + q * 4 + i;
        const float v = acc[mt][nt][i] + bb;
        if constexpr (MODE == 1) outf[(size_t)row * NC + col] = v;
        else                     outb[(size_t)row * NC + col] = f2bf(v);
      }
    }
  }
}

// ---------------------------------------------------------------------------
// LSTM cell: f = sum_k sig(pre_fk)*c_k ; gates ; c (f32), h (bf16), t += h (f32)
// ---------------------------------------------------------------------------
__global__ __launch_bounds__(256) void cell_k(
    const u16* __restrict__ pre, const int* __restrict__ idxs,
    const float* __restrict__ c_prev, float* __restrict__ c_cur,
    u16* __restrict__ h_cur, float* __restrict__ t_io)
{
  const int g = blockIdx.x * 256 + threadIdx.x;
  const int r = g >> 7;
  const int j = g & 127;
  const u16* pr = pre + (size_t)r * NC_STEP;
  float f = 0.f;
#pragma unroll
  for (int k = 0; k < KCH; ++k) {
    const int id = idxs[r * KCH + k];
    const float cg = (id >= 1) ? c_prev[(size_t)(id - 1) * HD + j] : 0.f;
    f += sigm(bf2f(pr[k * HD + j])) * cg;
  }
  const float iv = sigm(bf2f(pr[4 * HD + j]));
  const float uv = tanh_fast(bf2f(pr[5 * HD + j]));
  const float ov = sigm(bf2f(pr[6 * HD + j]));
  const float cn = iv * uv + f;
  const float hv = ov * tanh_fast(cn);
  c_cur[g] = cn;
  h_cur[g] = f2bf(hv);
  t_io[g] = t_io[g] + hv;
}

__global__ __launch_bounds__(256) void conv_k(const float* __restrict__ src,
                                              u16* __restrict__ dst, int n4)
{
  const int g = blockIdx.x * 256 + threadIdx.x;
  if (g < n4) {
    float4 v = ((const float4*)src)[g];
    ((ushort4*)dst)[g] = make_ushort4(f2bf(v.x), f2bf(v.y), f2bf(v.z), f2bf(v.w));
  }
}

// Build U_big[l][896][640] (bf16) = [Uf;Uiuo | W_w(mapped)] + fused f32 biases.
__global__ __launch_bounds__(256) void prep_k(
    const float* __restrict__ Uf_w, const float* __restrict__ Uf_b,
    const float* __restrict__ Uiuo_w, const float* __restrict__ Uiuo_b,
    const float* __restrict__ W_w, const float* __restrict__ W_b,
    u16* __restrict__ Ubig, float* __restrict__ biasbig)
{
  const int l = blockIdx.y;
  const int e = blockIdx.x * 256 + threadIdx.x;
  const int c = e / KD_STEP;
  const int k = e % KD_STEP;
  float v;
  if (k < 512) {
    v = (c < 512) ? Uf_w[((size_t)l * 512 + c) * 512 + k]
                  : Uiuo_w[((size_t)l * 384 + (c - 512)) * 512 + k];
  } else {
    const int q = k - 512;
    const int wr = (c < 512) ? (c & 127) : (128 + (c - 512));
    v = W_w[((size_t)l * 512 + wr) * 128 + q];
  }
  Ubig[((size_t)l * 896 + c) * 640 + k] = f2bf(v);
  if (e < 896) {
    const float b = (e < 512)
        ? (Uf_b[l * 512 + e] + W_b[l * 512 + (e & 127)])
        : (Uiuo_b[l * 384 + (e - 512)] + W_b[l * 512 + 128 + (e - 512)]);
    biasbig[l * 896 + e] = b;
  }
}

// Output (FLOAT32): hx = tile(t_final,2), cx = tile(c_final,2).
__global__ __launch_bounds__(256) void fin_k(
    const float* __restrict__ t_fin, const float* __restrict__ c_fin,
    float* __restrict__ out)
{
  const size_t NH = (size_t)NNODE * HD;
  const size_t g = (size_t)blockIdx.x * 256 + threadIdx.x;
  const float h = t_fin[g];
  const float c = c_fin[g];
  out[g] = h;
  out[NH + g] = h;
  out[2 * NH + g] = c;
  out[3 * NH + g] = c;
}

extern "C" void kernel_launch(void* const* d_in, const int* in_sizes, int n_in,
                              void* d_out, int out_size, void* d_ws, size_t ws_size,
                              hipStream_t stream)
{
  (void)in_sizes; (void)n_in; (void)out_size; (void)ws_size;
  const int*   tokens  = (const int*)d_in[0];
  const int*   indices = (const int*)d_in[1];
  const float* E       = (const float*)d_in[2];
  const float* lin_w   = (const float*)d_in[3];
  const float* lin_b   = (const float*)d_in[4];
  const float* Uf_w    = (const float*)d_in[5];
  const float* Uf_b    = (const float*)d_in[6];
  const float* Uiuo_w  = (const float*)d_in[7];
  const float* Uiuo_b  = (const float*)d_in[8];
  const float* W_w     = (const float*)d_in[9];
  const float* W_b     = (const float*)d_in[10];
  float* out = (float*)d_out;   // FLOAT32 output (R8-proven)

  const size_t NH = (size_t)NNODE * HD;

  char* ws = (char*)d_ws;
  size_t off = 0;
  auto alloc = [&](size_t bytes) -> void* {
    void* p = ws + off;
    off = (off + bytes + 255) & ~(size_t)255;
    return p;
  };
  u16*   Ubig    = (u16*)alloc((size_t)2 * 896 * 640 * 2);
  float* biasbig = (float*)alloc(2 * 896 * 4);
  u16*   Ebf     = (u16*)alloc((size_t)50000 * HD * 2);
  u16*   Lbf     = (u16*)alloc((size_t)HD * KD_EMB * 2);
  float* tslice  = (float*)alloc(NH * 4);
  u16*   h0a     = (u16*)alloc(NH * 2);
  u16*   h0b     = (u16*)alloc(NH * 2);
  u16*   h1a     = (u16*)alloc(NH * 2);
  u16*   h1b     = (u16*)alloc(NH * 2);
  float* c0a     = (float*)alloc(NH * 4);
  float* c0b     = (float*)alloc(NH * 4);
  float* c1a     = (float*)alloc(NH * 4);
  float* c1b     = (float*)alloc(NH * 4);
  u16*   pre     = (u16*)alloc((size_t)NNODE * NC_STEP * 2);
  u16*   zbuf    = (u16*)alloc(512);

  u16*   h0[2] = {h0a, h0b};
  u16*   h1[2] = {h1a, h1b};
  float* c0[2] = {c0a, c0b};
  float* c1[2] = {c1a, c1b};

  hipMemsetAsync(zbuf, 0, 512, stream);
  hipMemsetAsync(h0[0], 0, NH * 2, stream);
  hipMemsetAsync(h1[0], 0, NH * 2, stream);
  hipMemsetAsync(c0[0], 0, NH * 4, stream);
  hipMemsetAsync(c1[0], 0, NH * 4, stream);
  prep_k<<<dim3(2240, 2), 256, 0, stream>>>(Uf_w, Uf_b, Uiuo_w, Uiuo_b, W_w, W_b,
                                            Ubig, biasbig);
  conv_k<<<dim3((50000 * HD / 4 + 255) / 256), 256, 0, stream>>>(E, Ebf, 50000 * HD / 4);
  conv_k<<<dim3((HD * KD_EMB / 4 + 255) / 256), 256, 0, stream>>>(lin_w, Lbf, HD * KD_EMB / 4);

  for (int d = 0; d < DD; ++d) {
    const int ri = d & 1, wi = (d + 1) & 1;
    const int* idxd = indices + (size_t)d * NNODE * KCH;
    const int* tokd = tokens + (size_t)d * NNODE * LTOK;

    // tslice (f32) = gather(Ebf, tokens[d]) @ Lbf^T + lin_b
    gemm_k<1, NC_EMB, KD_EMB><<<dim3(NNODE / 128, 1), 256, 0, stream>>>(
        Ebf, nullptr, tokd, Lbf, lin_b, nullptr, tslice, zbuf);

    for (int l = 0; l < 2; ++l) {
      const u16*   hp = (l == 0) ? h0[ri] : h1[ri];
      u16*         hc = (l == 0) ? h0[wi] : h1[wi];
      const float* cp = (l == 0) ? c0[ri] : c1[ri];
      float*       cc = (l == 0) ? c0[wi] : c1[wi];
      const u16* Ul = Ubig + (size_t)l * 896 * 640;
      const float* bl = biasbig + l * 896;
      gemm_k<0, NC_STEP, KD_STEP><<<dim3(NNODE / 128, NC_STEP / 128), 256, 0, stream>>>(
          hp, tslice, idxd, Ul, bl, pre, nullptr, zbuf);
      cell_k<<<dim3((int)(NH / 256)), 256, 0, stream>>>(
          pre, idxd, cp, cc, hc, tslice);
    }
  }
  // after d=11: tslice = t_final, c1[0] = c_final
  fin_k<<<dim3((int)(NH / 256)), 256, 0, stream>>>(tslice, c1[0], out);
}